// Round 3
// baseline (438.668 us; speedup 1.0000x reference)
//
#include <hip/hip_runtime.h>

#define N_NODES 50000
#define E_EDGES 600000
#define LLM_DIM 640
#define HIDDEN 128
#define POUT 112
#define NB_SCAN 98   // ceil(50000/512)

typedef __attribute__((ext_vector_type(8))) short bf16x8;
typedef __attribute__((ext_vector_type(4))) float f32x4;

__device__ inline unsigned short f2bf(float f) {
    unsigned u = __float_as_uint(f);
    u += 0x7fff + ((u >> 16) & 1);   // RNE
    return (unsigned short)(u >> 16);
}
__device__ inline unsigned pkbf(float a, float b) {
    return (unsigned)f2bf(a) | ((unsigned)f2bf(b) << 16);
}
__device__ inline float bflo(unsigned v) { return __uint_as_float(v << 16); }
__device__ inline float bfhi(unsigned v) { return __uint_as_float(v & 0xffff0000u); }

// ---------------- degree count (int) ----------------
__global__ void deg_count(const int* __restrict__ eidx, int* __restrict__ cnt) {
    int e = blockIdx.x * 256 + threadIdx.x;
    if (e < E_EDGES) atomicAdd(&cnt[eidx[E_EDGES + e]], 1);
}

__global__ void make_dis(const int* __restrict__ cnt, float* __restrict__ dis) {
    int i = blockIdx.x * 256 + threadIdx.x;
    if (i < N_NODES) dis[i] = rsqrtf(1.0f + (float)cnt[i]);
}

// ---------------- 3-kernel exclusive scan over cnt -> offs ----------------
__global__ __launch_bounds__(256) void scan_blocksum(const int* __restrict__ cnt, int* __restrict__ bsum) {
    __shared__ int s[256];
    int b = blockIdx.x, t = threadIdx.x;
    int i0 = b * 512 + t, i1 = i0 + 256;
    int v = (i0 < N_NODES ? cnt[i0] : 0) + (i1 < N_NODES ? cnt[i1] : 0);
    s[t] = v;
    __syncthreads();
    for (int st = 128; st; st >>= 1) {
        if (t < st) s[t] += s[t + st];
        __syncthreads();
    }
    if (t == 0) bsum[b] = s[0];
}

__global__ void scan_bsum(const int* __restrict__ bsum, int* __restrict__ bpre) {
    __shared__ int s[128];
    int t = threadIdx.x;
    if (t < NB_SCAN) s[t] = bsum[t];
    __syncthreads();
    if (t == 0) {
        int a = 0;
        for (int i = 0; i < NB_SCAN; i++) { int v = s[i]; s[i] = a; a += v; }
    }
    __syncthreads();
    if (t < NB_SCAN) bpre[t] = s[t];
}

__global__ __launch_bounds__(256) void scan_offs(const int* __restrict__ cnt, const int* __restrict__ bpre,
                                                 int* __restrict__ offs) {
    __shared__ int sA[512], sB[512];
    int b = blockIdx.x, t = threadIdx.x;
    int i0 = b * 512 + t, i1 = i0 + 256;
    int v0 = (i0 < N_NODES ? cnt[i0] : 0);
    int v1 = (i1 < N_NODES ? cnt[i1] : 0);
    sA[t] = v0; sA[t + 256] = v1;
    int* src = sA; int* dst = sB;
    for (int st = 1; st < 512; st <<= 1) {
        __syncthreads();
        dst[t]       = src[t]       + (t       >= st ? src[t - st]       : 0);
        dst[t + 256] = src[t + 256] + (t + 256 >= st ? src[t + 256 - st] : 0);
        int* tmp = src; src = dst; dst = tmp;
    }
    __syncthreads();
    int base = bpre[b];
    if (i0 < N_NODES) offs[i0] = base + src[t] - v0;
    if (i1 < N_NODES) offs[i1] = base + src[t + 256] - v1;
    if (b == 0 && t == 0) offs[N_NODES] = E_EDGES;
}

__global__ void fill_srcs(const int* __restrict__ eidx, const int* __restrict__ offs,
                          int* __restrict__ pos, int* __restrict__ srcs) {
    int e = blockIdx.x * 256 + threadIdx.x;
    if (e >= E_EDGES) return;
    int s = eidx[e];
    int d = eidx[E_EDGES + e];
    int p = atomicAdd(&pos[d], 1);
    srcs[offs[d] + p] = s;
}

// ---------------- weight converts ----------------
__global__ void wt_convert(const float* __restrict__ W, unsigned short* __restrict__ Wt) {
    int idx = blockIdx.x * 256 + threadIdx.x;
    if (idx >= POUT * LLM_DIM) return;
    int n = idx / LLM_DIM;
    int k = idx - n * LLM_DIM;
    Wt[(size_t)n * LLM_DIM + k] = f2bf(W[(size_t)k * POUT + n]);
}

__global__ void w2_convert(const float* __restrict__ W, unsigned short* __restrict__ Wt2) {
    int idx = blockIdx.x * 256 + threadIdx.x;
    if (idx >= 2 * HIDDEN * HIDDEN) return;
    int l = idx >> 14;
    int rem = idx & 16383;
    int n = rem >> 7;
    int k = rem & 127;
    Wt2[idx] = f2bf(W[l * 16384 + k * 128 + n]);
}

// ---------------- projection: stage WHOLE A-tile once (linear stream), then barrier-free K-loop ----------------
// A tile 64x640 fp32 read as one linear 160 KB stream (max MLP, DRAM-friendly), converted to
// bf16 in regs, stored to XOR-swizzled LDS (80 KB). K-loop: 1 ds_read_b128 (lgkm) + 7 L2-hot
// B loads (vmcnt, double-buffered) + 7 MFMA per step; zero barriers, zero global-A dependency.
// Swizzle: 16B slot phys = sl ^ (row&7), same involution on write and read.
__global__ __launch_bounds__(256) void proj_mfma(const float* __restrict__ A,
                                                 const unsigned short* __restrict__ Wt,
                                                 const float* __restrict__ bias,
                                                 const float* __restrict__ emb,
                                                 const int* __restrict__ sid,
                                                 const float* __restrict__ dis,
                                                 float* __restrict__ X,
                                                 unsigned short* __restrict__ Xs) {
    __shared__ __align__(16) unsigned short As[64 * 640];   // 80 KB -> exactly 2 blocks/CU
    const int tid  = threadIdx.x;
    const int wave = tid >> 6, lane = tid & 63;
    const int l15 = lane & 15, l4 = lane >> 4;
    const int row0 = blockIdx.x * 64;

    // ---- stage: 5120 16B-slots (64 rows x 80 slots), 20 slots/thread, 2 halves of 10 ----
#pragma unroll
    for (int half = 0; half < 2; half++) {
        float4 v[20];
        int lidx[10];
#pragma unroll
        for (int j = 0; j < 10; j++) {
            int s = (half * 10 + j) * 256 + tid;
            int row = s / 80;
            int sl = s - row * 80;
            int phys = sl ^ (row & 7);
            lidx[j] = row * 640 + phys * 8;
            int grow = row0 + row; if (grow >= N_NODES) grow = N_NODES - 1;
            const float4* gp = reinterpret_cast<const float4*>(A + (size_t)grow * LLM_DIM + sl * 8);
            v[2 * j]     = gp[0];
            v[2 * j + 1] = gp[1];
        }
#pragma unroll
        for (int j = 0; j < 10; j++) {
            uint4 u;
            u.x = pkbf(v[2 * j].x,     v[2 * j].y);
            u.y = pkbf(v[2 * j].z,     v[2 * j].w);
            u.z = pkbf(v[2 * j + 1].x, v[2 * j + 1].y);
            u.w = pkbf(v[2 * j + 1].z, v[2 * j + 1].w);
            *reinterpret_cast<uint4*>(&As[lidx[j]]) = u;
        }
    }

    // B fragment base (L2-hot 143 KB weight) -- issue prologue loads before the barrier
    const unsigned short* Bp = Wt + (size_t)l15 * LLM_DIM + l4 * 8;
    bf16x8 bc[7], bn[7];
#pragma unroll
    for (int ct = 0; ct < 7; ct++)
        bc[ct] = *reinterpret_cast<const bf16x8*>(Bp + (size_t)ct * 16 * LLM_DIM);

    __syncthreads();   // the only barrier

    const int arow = wave * 16 + l15;
    const int abase = arow * 640;
    const int rsw = l15 & 7;

    f32x4 acc[7];
#pragma unroll
    for (int j = 0; j < 7; j++) acc[j] = (f32x4){0.f, 0.f, 0.f, 0.f};

#pragma unroll
    for (int ks2 = 0; ks2 < 10; ks2++) {
        const int ks0 = ks2 * 2;
        // even step: prefetch B[ks0+1] -> bn, compute with bc
        {
#pragma unroll
            for (int ct = 0; ct < 7; ct++)
                bn[ct] = *reinterpret_cast<const bf16x8*>(Bp + (size_t)ct * 16 * LLM_DIM + (ks0 + 1) * 32);
            int phys = (ks0 * 4 + l4) ^ rsw;
            bf16x8 a = *reinterpret_cast<const bf16x8*>(&As[abase + phys * 8]);
#pragma unroll
            for (int ct = 0; ct < 7; ct++)
                acc[ct] = __builtin_amdgcn_mfma_f32_16x16x32_bf16(a, bc[ct], acc[ct], 0, 0, 0);
        }
        // odd step: prefetch B[ks0+2] -> bc, compute with bn
        {
            if (ks2 < 9) {
#pragma unroll
                for (int ct = 0; ct < 7; ct++)
                    bc[ct] = *reinterpret_cast<const bf16x8*>(Bp + (size_t)ct * 16 * LLM_DIM + (ks0 + 2) * 32);
            }
            int phys = ((ks0 + 1) * 4 + l4) ^ rsw;
            bf16x8 a = *reinterpret_cast<const bf16x8*>(&As[abase + phys * 8]);
#pragma unroll
            for (int ct = 0; ct < 7; ct++)
                acc[ct] = __builtin_amdgcn_mfma_f32_16x16x32_bf16(a, bn[ct], acc[ct], 0, 0, 0);
        }
    }

    // epilogue: rows row0 + wave*16 + l4*4 + r; cols ct*16 + l15 (+ emb cols 112..127)
#pragma unroll
    for (int r = 0; r < 4; r++) {
        int row = row0 + wave * 16 + l4 * 4 + r;
        if (row >= N_NODES) continue;
        float d = dis[row];
#pragma unroll
        for (int ct = 0; ct < 7; ct++) {
            int col = ct * 16 + l15;
            float v = acc[ct][r] + bias[col];
            X[(size_t)row * HIDDEN + col] = v;
            Xs[(size_t)row * HIDDEN + col] = f2bf(d * v);
        }
        float e = emb[sid[row] * 16 + l15];
        X[(size_t)row * HIDDEN + POUT + l15] = e;
        Xs[(size_t)row * HIDDEN + POUT + l15] = f2bf(d * e);
    }
}

// ---------------- CSR gather on bf16: Gb[i] = bf16(dis_i*(sum Xs[src] + Xs[i])) ----------------
// Xs already carries one dis factor; self-loop term is dis_i^2*x_i = dis_i*Xs_i.
__global__ __launch_bounds__(256) void gather(const unsigned short* __restrict__ Xs,
                                              const int* __restrict__ offs,
                                              const int* __restrict__ srcs,
                                              const float* __restrict__ dis,
                                              unsigned short* __restrict__ Gb) {
    int node = blockIdx.x * 4 + (threadIdx.x >> 6);
    int lane = threadIdx.x & 63;
    if (node >= N_NODES) return;
    int beg = __builtin_amdgcn_readfirstlane(offs[node]);
    int end = __builtin_amdgcn_readfirstlane(offs[node + 1]);
    const unsigned* X32 = reinterpret_cast<const unsigned*>(Xs);
    float ax = 0.f, ay = 0.f;
    int e = beg;
    while (e < end) {
        int n = end - e;
        if (n > 64) n = 64;
        int idx = (lane < n) ? srcs[e + lane] : 0;
        int j = 0;
        for (; j + 4 <= n; j += 4) {
            int s0 = __shfl(idx, j);
            int s1 = __shfl(idx, j + 1);
            int s2 = __shfl(idx, j + 2);
            int s3 = __shfl(idx, j + 3);
            unsigned v0 = X32[(size_t)s0 * 64 + lane];
            unsigned v1 = X32[(size_t)s1 * 64 + lane];
            unsigned v2 = X32[(size_t)s2 * 64 + lane];
            unsigned v3 = X32[(size_t)s3 * 64 + lane];
            ax += (bflo(v0) + bflo(v1)) + (bflo(v2) + bflo(v3));
            ay += (bfhi(v0) + bfhi(v1)) + (bfhi(v2) + bfhi(v3));
        }
        for (; j < n; j++) {
            int s = __shfl(idx, j);
            unsigned v = X32[(size_t)s * 64 + lane];
            ax += bflo(v);
            ay += bfhi(v);
        }
        e += 64;
    }
    float d = dis[node];
    unsigned sv = X32[(size_t)node * 64 + lane];
    ax = d * (ax + bflo(sv));   // self term = dis_i * Xs_i
    ay = d * (ay + bfhi(sv));
    reinterpret_cast<unsigned*>(Gb)[(size_t)node * 64 + lane] =
        (unsigned)f2bf(ax) | ((unsigned)f2bf(ay) << 16);
}

// ---------------- fused GEMM + residual + relu (+Xs emit / +LayerNorm) ----------------
// MODE 0: X += relu(Gb@W + b); Xs2 = bf16(dis*X)
// MODE 1: X = LayerNorm(X + relu(Gb@W + b))
template <int MODE>
__global__ __launch_bounds__(256) void gemm_fin(const unsigned short* __restrict__ Gb,
                                                const unsigned short* __restrict__ Wt2,
                                                const float* __restrict__ bias,
                                                const float* __restrict__ dis,
                                                const float* __restrict__ lng,
                                                const float* __restrict__ lnb,
                                                float* __restrict__ X,
                                                unsigned short* __restrict__ Xs2) {
    __shared__ short As[64][136];    // K=128 + 8 pad
    __shared__ short Bs[128][136];
    const int tid = threadIdx.x;
    const int wave = tid >> 6, lane = tid & 63;
    const int row0 = blockIdx.x * 64;
    const int l15 = lane & 15, l4 = lane >> 4;

    // stage A 64x128 bf16: 1024 uint4, 4/thread
#pragma unroll
    for (int i = 0; i < 4; i++) {
        int f = i * 256 + tid;
        int r = f >> 4;
        int q = f & 15;
        int grow = row0 + r;
        uint4 v = make_uint4(0, 0, 0, 0);
        if (grow < N_NODES)
            v = reinterpret_cast<const uint4*>(Gb + (size_t)grow * HIDDEN)[q];
        *reinterpret_cast<uint4*>(&As[r][q * 8]) = v;
    }
    // stage B 128x128 bf16: 2048 uint4, 8/thread
#pragma unroll
    for (int i = 0; i < 8; i++) {
        int f = i * 256 + tid;
        int r = f >> 4;
        int q = f & 15;
        uint4 v = reinterpret_cast<const uint4*>(Wt2 + (size_t)r * HIDDEN)[q];
        *reinterpret_cast<uint4*>(&Bs[r][q * 8]) = v;
    }
    __syncthreads();

    f32x4 acc[8];
#pragma unroll
    for (int j = 0; j < 8; j++) acc[j] = (f32x4){0.f, 0.f, 0.f, 0.f};
#pragma unroll
    for (int ks = 0; ks < 4; ks++) {
        int kk = ks * 32 + l4 * 8;
        bf16x8 a = *reinterpret_cast<bf16x8*>(&As[wave * 16 + l15][kk]);
#pragma unroll
        for (int ct = 0; ct < 8; ct++) {
            bf16x8 b = *reinterpret_cast<bf16x8*>(&Bs[ct * 16 + l15][kk]);
            acc[ct] = __builtin_amdgcn_mfma_f32_16x16x32_bf16(a, b, acc[ct], 0, 0, 0);
        }
    }

    // epilogue
    float bcol[8];
#pragma unroll
    for (int ct = 0; ct < 8; ct++) bcol[ct] = bias[ct * 16 + l15];

    float vv[8][4];
#pragma unroll
    for (int r = 0; r < 4; r++) {
        int row = row0 + wave * 16 + l4 * 4 + r;
        bool ok = row < N_NODES;
#pragma unroll
        for (int ct = 0; ct < 8; ct++) {
            float xo = ok ? X[(size_t)row * HIDDEN + ct * 16 + l15] : 0.f;
            vv[ct][r] = xo + fmaxf(acc[ct][r] + bcol[ct], 0.f);
        }
    }

    if (MODE == 0) {
#pragma unroll
        for (int r = 0; r < 4; r++) {
            int row = row0 + wave * 16 + l4 * 4 + r;
            if (row >= N_NODES) continue;
            float d = dis[row];
#pragma unroll
            for (int ct = 0; ct < 8; ct++) {
                int col = ct * 16 + l15;
                X[(size_t)row * HIDDEN + col] = vv[ct][r];
                Xs2[(size_t)row * HIDDEN + col] = f2bf(d * vv[ct][r]);
            }
        }
    } else {
        float s[4], q2[4];
#pragma unroll
        for (int r = 0; r < 4; r++) {
            s[r] = 0.f; q2[r] = 0.f;
#pragma unroll
            for (int ct = 0; ct < 8; ct++) {
                s[r] += vv[ct][r];
                q2[r] += vv[ct][r] * vv[ct][r];
            }
        }
#pragma unroll
        for (int off = 1; off < 16; off <<= 1) {
#pragma unroll
            for (int r = 0; r < 4; r++) {
                s[r] += __shfl_xor(s[r], off);
                q2[r] += __shfl_xor(q2[r], off);
            }
        }
        float gcol[8], bcol2[8];
#pragma unroll
        for (int ct = 0; ct < 8; ct++) {
            gcol[ct] = lng[ct * 16 + l15];
            bcol2[ct] = lnb[ct * 16 + l15];
        }
#pragma unroll
        for (int r = 0; r < 4; r++) {
            int row = row0 + wave * 16 + l4 * 4 + r;
            if (row >= N_NODES) continue;
            float mean = s[r] * (1.f / 128.f);
            float var = q2[r] * (1.f / 128.f) - mean * mean;
            float inv = rsqrtf(var + 1e-5f);
#pragma unroll
            for (int ct = 0; ct < 8; ct++) {
                int col = ct * 16 + l15;
                X[(size_t)row * HIDDEN + col] = (vv[ct][r] - mean) * inv * gcol[ct] + bcol2[ct];
            }
        }
    }
}

extern "C" void kernel_launch(void* const* d_in, const int* in_sizes, int n_in,
                              void* d_out, int out_size, void* d_ws, size_t ws_size,
                              hipStream_t stream) {
    const float* llm   = (const float*)d_in[0];
    const int*   sid   = (const int*)d_in[1];
    const int*   eidx  = (const int*)d_in[2];
    const float* projW = (const float*)d_in[3];
    const float* projb = (const float*)d_in[4];
    const float* emb   = (const float*)d_in[5];
    const float* gcnW  = (const float*)d_in[6];
    const float* gcnb  = (const float*)d_in[7];
    const float* lng   = (const float*)d_in[8];
    const float* lnb   = (const float*)d_in[9];

    float* X = (float*)d_out;                                   // [N,128] fp32
    unsigned short* Xs = (unsigned short*)d_ws;                 // [N,128] bf16
    unsigned short* Gb = Xs + (size_t)N_NODES * HIDDEN;         // [N,128] bf16
    unsigned short* Wt = Gb;                                    // [112,640] bf16 (overlaps Gb: dead before gather)
    unsigned short* Wt2 = Gb + (size_t)N_NODES * HIDDEN;        // [2,128,128] bf16
    float* dis = (float*)(Wt2 + 2 * HIDDEN * HIDDEN);           // [N]
    int* cnt  = (int*)(dis + N_NODES);                          // [N] (reused as pos)
    int* offs = cnt + N_NODES;                                  // [N+1]
    int* bsum = offs + N_NODES + 1;                             // [128]
    int* bpre = bsum + 128;                                     // [128]
    int* srcs = bpre + 128;                                     // [E]

    hipMemsetAsync(cnt, 0, N_NODES * sizeof(int), stream);
    deg_count<<<(E_EDGES + 255) / 256, 256, 0, stream>>>(eidx, cnt);
    make_dis<<<(N_NODES + 255) / 256, 256, 0, stream>>>(cnt, dis);
    scan_blocksum<<<NB_SCAN, 256, 0, stream>>>(cnt, bsum);
    scan_bsum<<<1, 128, 0, stream>>>(bsum, bpre);
    scan_offs<<<NB_SCAN, 256, 0, stream>>>(cnt, bpre, offs);
    hipMemsetAsync(cnt, 0, N_NODES * sizeof(int), stream);      // cnt -> pos
    fill_srcs<<<(E_EDGES + 255) / 256, 256, 0, stream>>>(eidx, offs, cnt, srcs);

    wt_convert<<<(POUT * LLM_DIM + 255) / 256, 256, 0, stream>>>(projW, Wt);
    w2_convert<<<(2 * HIDDEN * HIDDEN + 255) / 256, 256, 0, stream>>>(gcnW, Wt2);

    proj_mfma<<<(N_NODES + 63) / 64, 256, 0, stream>>>(llm, Wt, projb, emb, sid, dis, X, Xs);

    gather<<<(N_NODES + 3) / 4, 256, 0, stream>>>(Xs, offs, srcs, dis, Gb);
    gemm_fin<0><<<(N_NODES + 63) / 64, 256, 0, stream>>>(Gb, Wt2, gcnb, dis, lng, lnb, X, Xs);
    gather<<<(N_NODES + 3) / 4, 256, 0, stream>>>(Xs, offs, srcs, dis, Gb);
    gemm_fin<1><<<(N_NODES + 63) / 64, 256, 0, stream>>>(Gb, Wt2 + HIDDEN * HIDDEN, gcnb + HIDDEN, dis, lng, lnb, X, Xs);
}

// Round 4
// 375.079 us; speedup vs baseline: 1.1695x; 1.1695x over previous
//
#include <hip/hip_runtime.h>

#define N_NODES 50000
#define E_EDGES 600000
#define LLM_DIM 640
#define HIDDEN 128
#define POUT 112
#define NB_SCAN 98   // ceil(50000/512)

typedef __attribute__((ext_vector_type(8))) short bf16x8;
typedef __attribute__((ext_vector_type(4))) float f32x4;

__device__ inline unsigned short f2bf(float f) {
    unsigned u = __float_as_uint(f);
    u += 0x7fff + ((u >> 16) & 1);   // RNE
    return (unsigned short)(u >> 16);
}
__device__ inline float bflo(unsigned v) { return __uint_as_float(v << 16); }
__device__ inline float bfhi(unsigned v) { return __uint_as_float(v & 0xffff0000u); }

// ---------------- degree count (int) ----------------
__global__ void deg_count(const int* __restrict__ eidx, int* __restrict__ cnt) {
    int e = blockIdx.x * 256 + threadIdx.x;
    if (e < E_EDGES) atomicAdd(&cnt[eidx[E_EDGES + e]], 1);
}

__global__ void make_dis(const int* __restrict__ cnt, float* __restrict__ dis) {
    int i = blockIdx.x * 256 + threadIdx.x;
    if (i < N_NODES) dis[i] = rsqrtf(1.0f + (float)cnt[i]);
}

// ---------------- 3-kernel exclusive scan over cnt -> offs ----------------
__global__ __launch_bounds__(256) void scan_blocksum(const int* __restrict__ cnt, int* __restrict__ bsum) {
    __shared__ int s[256];
    int b = blockIdx.x, t = threadIdx.x;
    int i0 = b * 512 + t, i1 = i0 + 256;
    int v = (i0 < N_NODES ? cnt[i0] : 0) + (i1 < N_NODES ? cnt[i1] : 0);
    s[t] = v;
    __syncthreads();
    for (int st = 128; st; st >>= 1) {
        if (t < st) s[t] += s[t + st];
        __syncthreads();
    }
    if (t == 0) bsum[b] = s[0];
}

__global__ void scan_bsum(const int* __restrict__ bsum, int* __restrict__ bpre) {
    __shared__ int s[128];
    int t = threadIdx.x;
    if (t < NB_SCAN) s[t] = bsum[t];
    __syncthreads();
    if (t == 0) {
        int a = 0;
        for (int i = 0; i < NB_SCAN; i++) { int v = s[i]; s[i] = a; a += v; }
    }
    __syncthreads();
    if (t < NB_SCAN) bpre[t] = s[t];
}

__global__ __launch_bounds__(256) void scan_offs(const int* __restrict__ cnt, const int* __restrict__ bpre,
                                                 int* __restrict__ offs) {
    __shared__ int sA[512], sB[512];
    int b = blockIdx.x, t = threadIdx.x;
    int i0 = b * 512 + t, i1 = i0 + 256;
    int v0 = (i0 < N_NODES ? cnt[i0] : 0);
    int v1 = (i1 < N_NODES ? cnt[i1] : 0);
    sA[t] = v0; sA[t + 256] = v1;
    int* src = sA; int* dst = sB;
    for (int st = 1; st < 512; st <<= 1) {
        __syncthreads();
        dst[t]       = src[t]       + (t       >= st ? src[t - st]       : 0);
        dst[t + 256] = src[t + 256] + (t + 256 >= st ? src[t + 256 - st] : 0);
        int* tmp = src; src = dst; dst = tmp;
    }
    __syncthreads();
    int base = bpre[b];
    if (i0 < N_NODES) offs[i0] = base + src[t] - v0;
    if (i1 < N_NODES) offs[i1] = base + src[t + 256] - v1;
    if (b == 0 && t == 0) offs[N_NODES] = E_EDGES;
}

__global__ void fill_srcs(const int* __restrict__ eidx, const int* __restrict__ offs,
                          int* __restrict__ pos, int* __restrict__ srcs) {
    int e = blockIdx.x * 256 + threadIdx.x;
    if (e >= E_EDGES) return;
    int s = eidx[e];
    int d = eidx[E_EDGES + e];
    int p = atomicAdd(&pos[d], 1);
    srcs[offs[d] + p] = s;
}

// ---------------- merged weight convert (proj W transpose + gcn W transpose) ----------------
__global__ void conv_weights(const float* __restrict__ Wp, const float* __restrict__ Wg,
                             unsigned short* __restrict__ Wt, unsigned short* __restrict__ Wt2) {
    int idx = blockIdx.x * 256 + threadIdx.x;
    if (idx < POUT * LLM_DIM) {
        int n = idx / LLM_DIM;
        int k = idx - n * LLM_DIM;
        Wt[(size_t)n * LLM_DIM + k] = f2bf(Wp[(size_t)k * POUT + n]);
    } else {
        int i2 = idx - POUT * LLM_DIM;
        if (i2 < 2 * HIDDEN * HIDDEN) {
            int l = i2 >> 14;
            int rem = i2 & 16383;
            int n = rem >> 7;
            int k = rem & 127;
            Wt2[i2] = f2bf(Wg[l * 16384 + k * 128 + n]);
        }
    }
}

// ---------------- projection via bf16 MFMA, BM=64, fused struct-emb + Xs emit (r0 verbatim) ----------------
__global__ __launch_bounds__(256) void proj_mfma(const float* __restrict__ A,
                                                 const unsigned short* __restrict__ Wt,
                                                 const float* __restrict__ bias,
                                                 const float* __restrict__ emb,
                                                 const int* __restrict__ sid,
                                                 const float* __restrict__ dis,
                                                 float* __restrict__ X,
                                                 unsigned short* __restrict__ Xs) {
    __shared__ short As[64][72];    // K-tile 64 + pad
    __shared__ short Bs[112][72];
    const int tid = threadIdx.x;
    const int wave = tid >> 6, lane = tid & 63;
    const int row0 = blockIdx.x * 64;
    const int l15 = lane & 15, l4 = lane >> 4;

    f32x4 acc[7];
#pragma unroll
    for (int j = 0; j < 7; j++) acc[j] = (f32x4){0.f, 0.f, 0.f, 0.f};

    for (int k0 = 0; k0 < LLM_DIM; k0 += 64) {
        // A tile 64x64 fp32 -> bf16 LDS. 1024 float4, 4/thread, coalesced per row.
#pragma unroll
        for (int i = 0; i < 4; i++) {
            int f = i * 256 + tid;
            int r = f >> 4;          // 16 float4 per row
            int q = f & 15;
            int grow = row0 + r;
            float4 v = make_float4(0.f, 0.f, 0.f, 0.f);
            if (grow < N_NODES)
                v = *reinterpret_cast<const float4*>(A + (size_t)grow * LLM_DIM + k0 + q * 4);
            uint2 u;
            u.x = (unsigned)f2bf(v.x) | ((unsigned)f2bf(v.y) << 16);
            u.y = (unsigned)f2bf(v.z) | ((unsigned)f2bf(v.w) << 16);
            *reinterpret_cast<uint2*>(&As[r][q * 4]) = u;
        }
        // B tile 112x64 bf16. 1792 8B chunks, 7/thread.
#pragma unroll
        for (int i = 0; i < 7; i++) {
            int f = i * 256 + tid;
            int n = f >> 4;
            int q = f & 15;
            uint2 v = *reinterpret_cast<const uint2*>(Wt + (size_t)n * LLM_DIM + k0 + q * 4);
            *reinterpret_cast<uint2*>(&Bs[n][q * 4]) = v;
        }
        __syncthreads();
#pragma unroll
        for (int ks = 0; ks < 2; ks++) {
            int kk = ks * 32 + l4 * 8;
            bf16x8 a = *reinterpret_cast<bf16x8*>(&As[wave * 16 + l15][kk]);
#pragma unroll
            for (int ct = 0; ct < 7; ct++) {
                bf16x8 b = *reinterpret_cast<bf16x8*>(&Bs[ct * 16 + l15][kk]);
                acc[ct] = __builtin_amdgcn_mfma_f32_16x16x32_bf16(a, b, acc[ct], 0, 0, 0);
            }
        }
        __syncthreads();
    }
    // epilogue: rows row0 + wave*16 + l4*4 + r; cols ct*16 + l15 (+ emb cols 112..127)
#pragma unroll
    for (int r = 0; r < 4; r++) {
        int row = row0 + wave * 16 + l4 * 4 + r;
        if (row >= N_NODES) continue;
        float d = dis[row];
#pragma unroll
        for (int ct = 0; ct < 7; ct++) {
            int col = ct * 16 + l15;
            float v = acc[ct][r] + bias[col];
            X[(size_t)row * HIDDEN + col] = v;
            Xs[(size_t)row * HIDDEN + col] = f2bf(d * v);
        }
        float e = emb[sid[row] * 16 + l15];
        X[(size_t)row * HIDDEN + POUT + l15] = e;
        Xs[(size_t)row * HIDDEN + POUT + l15] = f2bf(d * e);
    }
}

// ---------------- CSR gather on bf16: Gb[i] = bf16(dis_i*(sum Xs[src] + Xs[i])) ----------------
// MLP widened to 8 rows in flight; masked 4-wide tail (no scalar-serial remainder).
__global__ __launch_bounds__(256) void gather(const unsigned short* __restrict__ Xs,
                                              const int* __restrict__ offs,
                                              const int* __restrict__ srcs,
                                              const float* __restrict__ dis,
                                              unsigned short* __restrict__ Gb) {
    int node = blockIdx.x * 4 + (threadIdx.x >> 6);
    int lane = threadIdx.x & 63;
    if (node >= N_NODES) return;
    int beg = __builtin_amdgcn_readfirstlane(offs[node]);
    int end = __builtin_amdgcn_readfirstlane(offs[node + 1]);
    const unsigned* X32 = reinterpret_cast<const unsigned*>(Xs);
    float d = dis[node];                             // issued early
    unsigned sv = X32[(size_t)node * 64 + lane];     // self row issued early
    float ax = 0.f, ay = 0.f;
    int e = beg;
    while (e < end) {
        int n = end - e;
        if (n > 64) n = 64;
        int idx = (lane < n) ? srcs[e + lane] : 0;
        int j = 0;
        // 8 rows in flight
        for (; j + 8 <= n; j += 8) {
            int s0 = __shfl(idx, j);
            int s1 = __shfl(idx, j + 1);
            int s2 = __shfl(idx, j + 2);
            int s3 = __shfl(idx, j + 3);
            int s4 = __shfl(idx, j + 4);
            int s5 = __shfl(idx, j + 5);
            int s6 = __shfl(idx, j + 6);
            int s7 = __shfl(idx, j + 7);
            unsigned v0 = X32[(size_t)s0 * 64 + lane];
            unsigned v1 = X32[(size_t)s1 * 64 + lane];
            unsigned v2 = X32[(size_t)s2 * 64 + lane];
            unsigned v3 = X32[(size_t)s3 * 64 + lane];
            unsigned v4 = X32[(size_t)s4 * 64 + lane];
            unsigned v5 = X32[(size_t)s5 * 64 + lane];
            unsigned v6 = X32[(size_t)s6 * 64 + lane];
            unsigned v7 = X32[(size_t)s7 * 64 + lane];
            ax += ((bflo(v0) + bflo(v1)) + (bflo(v2) + bflo(v3)))
                + ((bflo(v4) + bflo(v5)) + (bflo(v6) + bflo(v7)));
            ay += ((bfhi(v0) + bfhi(v1)) + (bfhi(v2) + bfhi(v3)))
                + ((bfhi(v4) + bfhi(v5)) + (bfhi(v6) + bfhi(v7)));
        }
        // exact 4-wide
        if (j + 4 <= n) {
            int s0 = __shfl(idx, j);
            int s1 = __shfl(idx, j + 1);
            int s2 = __shfl(idx, j + 2);
            int s3 = __shfl(idx, j + 3);
            unsigned v0 = X32[(size_t)s0 * 64 + lane];
            unsigned v1 = X32[(size_t)s1 * 64 + lane];
            unsigned v2 = X32[(size_t)s2 * 64 + lane];
            unsigned v3 = X32[(size_t)s3 * 64 + lane];
            ax += (bflo(v0) + bflo(v1)) + (bflo(v2) + bflo(v3));
            ay += (bfhi(v0) + bfhi(v1)) + (bfhi(v2) + bfhi(v3));
            j += 4;
        }
        // masked tail (rem 0..3), loads stay parallel, duplicates masked out
        int rem = n - j;
        if (rem > 0) {
            int s0 = __shfl(idx, j);
            int s1 = __shfl(idx, j + (rem > 1 ? 1 : 0));
            int s2 = __shfl(idx, j + (rem > 2 ? 2 : 0));
            unsigned v0 = X32[(size_t)s0 * 64 + lane];
            unsigned v1 = X32[(size_t)s1 * 64 + lane];
            unsigned v2 = X32[(size_t)s2 * 64 + lane];
            ax += bflo(v0) + (rem > 1 ? bflo(v1) : 0.f) + (rem > 2 ? bflo(v2) : 0.f);
            ay += bfhi(v0) + (rem > 1 ? bfhi(v1) : 0.f) + (rem > 2 ? bfhi(v2) : 0.f);
        }
        e += 64;
    }
    ax = d * (ax + bflo(sv));   // self term = dis_i * Xs_i
    ay = d * (ay + bfhi(sv));
    reinterpret_cast<unsigned*>(Gb)[(size_t)node * 64 + lane] =
        (unsigned)f2bf(ax) | ((unsigned)f2bf(ay) << 16);
}

// ---------------- fused GEMM + residual + relu (+Xs emit / +LayerNorm) ----------------
// MODE 0: X += relu(Gb@W + b); Xs2 = bf16(dis*X)
// MODE 1: X = LayerNorm(X + relu(Gb@W + b))
// X residual loads hoisted before __syncthreads to overlap their latency with staging+MFMA.
template <int MODE>
__global__ __launch_bounds__(256) void gemm_fin(const unsigned short* __restrict__ Gb,
                                                const unsigned short* __restrict__ Wt2,
                                                const float* __restrict__ bias,
                                                const float* __restrict__ dis,
                                                const float* __restrict__ lng,
                                                const float* __restrict__ lnb,
                                                float* __restrict__ X,
                                                unsigned short* __restrict__ Xs2) {
    __shared__ short As[64][136];    // K=128 + 8 pad
    __shared__ short Bs[128][136];
    const int tid = threadIdx.x;
    const int wave = tid >> 6, lane = tid & 63;
    const int row0 = blockIdx.x * 64;
    const int l15 = lane & 15, l4 = lane >> 4;

    // stage A 64x128 bf16: 1024 uint4, 4/thread
#pragma unroll
    for (int i = 0; i < 4; i++) {
        int f = i * 256 + tid;
        int r = f >> 4;
        int q = f & 15;
        int grow = row0 + r;
        uint4 v = make_uint4(0, 0, 0, 0);
        if (grow < N_NODES)
            v = reinterpret_cast<const uint4*>(Gb + (size_t)grow * HIDDEN)[q];
        *reinterpret_cast<uint4*>(&As[r][q * 8]) = v;
    }
    // stage B 128x128 bf16: 2048 uint4, 8/thread
#pragma unroll
    for (int i = 0; i < 8; i++) {
        int f = i * 256 + tid;
        int r = f >> 4;
        int q = f & 15;
        uint4 v = reinterpret_cast<const uint4*>(Wt2 + (size_t)r * HIDDEN)[q];
        *reinterpret_cast<uint4*>(&Bs[r][q * 8]) = v;
    }

    // hoisted residual X loads (independent of LDS staging; overlap with barrier+MFMA)
    float xo[8][4];
#pragma unroll
    for (int r = 0; r < 4; r++) {
        int row = row0 + wave * 16 + l4 * 4 + r;
        int rc = row < N_NODES ? row : 0;
#pragma unroll
        for (int ct = 0; ct < 8; ct++)
            xo[ct][r] = X[(size_t)rc * HIDDEN + ct * 16 + l15];
    }

    __syncthreads();

    f32x4 acc[8];
#pragma unroll
    for (int j = 0; j < 8; j++) acc[j] = (f32x4){0.f, 0.f, 0.f, 0.f};
#pragma unroll
    for (int ks = 0; ks < 4; ks++) {
        int kk = ks * 32 + l4 * 8;
        bf16x8 a = *reinterpret_cast<bf16x8*>(&As[wave * 16 + l15][kk]);
#pragma unroll
        for (int ct = 0; ct < 8; ct++) {
            bf16x8 b = *reinterpret_cast<bf16x8*>(&Bs[ct * 16 + l15][kk]);
            acc[ct] = __builtin_amdgcn_mfma_f32_16x16x32_bf16(a, b, acc[ct], 0, 0, 0);
        }
    }

    // epilogue
    float bcol[8];
#pragma unroll
    for (int ct = 0; ct < 8; ct++) bcol[ct] = bias[ct * 16 + l15];

    float vv[8][4];
#pragma unroll
    for (int r = 0; r < 4; r++) {
        int row = row0 + wave * 16 + l4 * 4 + r;
        bool ok = row < N_NODES;
#pragma unroll
        for (int ct = 0; ct < 8; ct++) {
            float xv = ok ? xo[ct][r] : 0.f;
            vv[ct][r] = xv + fmaxf(acc[ct][r] + bcol[ct], 0.f);
        }
    }

    if (MODE == 0) {
#pragma unroll
        for (int r = 0; r < 4; r++) {
            int row = row0 + wave * 16 + l4 * 4 + r;
            if (row >= N_NODES) continue;
            float d = dis[row];
#pragma unroll
            for (int ct = 0; ct < 8; ct++) {
                int col = ct * 16 + l15;
                X[(size_t)row * HIDDEN + col] = vv[ct][r];
                Xs2[(size_t)row * HIDDEN + col] = f2bf(d * vv[ct][r]);
            }
        }
    } else {
        float s[4], q2[4];
#pragma unroll
        for (int r = 0; r < 4; r++) {
            s[r] = 0.f; q2[r] = 0.f;
#pragma unroll
            for (int ct = 0; ct < 8; ct++) {
                s[r] += vv[ct][r];
                q2[r] += vv[ct][r] * vv[ct][r];
            }
        }
#pragma unroll
        for (int off = 1; off < 16; off <<= 1) {
#pragma unroll
            for (int r = 0; r < 4; r++) {
                s[r] += __shfl_xor(s[r], off);
                q2[r] += __shfl_xor(q2[r], off);
            }
        }
        float gcol[8], bcol2[8];
#pragma unroll
        for (int ct = 0; ct < 8; ct++) {
            gcol[ct] = lng[ct * 16 + l15];
            bcol2[ct] = lnb[ct * 16 + l15];
        }
#pragma unroll
        for (int r = 0; r < 4; r++) {
            int row = row0 + wave * 16 + l4 * 4 + r;
            if (row >= N_NODES) continue;
            float mean = s[r] * (1.f / 128.f);
            float var = q2[r] * (1.f / 128.f) - mean * mean;
            float inv = rsqrtf(var + 1e-5f);
#pragma unroll
            for (int ct = 0; ct < 8; ct++) {
                int col = ct * 16 + l15;
                X[(size_t)row * HIDDEN + col] = (vv[ct][r] - mean) * inv * gcol[ct] + bcol2[ct];
            }
        }
    }
}

extern "C" void kernel_launch(void* const* d_in, const int* in_sizes, int n_in,
                              void* d_out, int out_size, void* d_ws, size_t ws_size,
                              hipStream_t stream) {
    const float* llm   = (const float*)d_in[0];
    const int*   sid   = (const int*)d_in[1];
    const int*   eidx  = (const int*)d_in[2];
    const float* projW = (const float*)d_in[3];
    const float* projb = (const float*)d_in[4];
    const float* emb   = (const float*)d_in[5];
    const float* gcnW  = (const float*)d_in[6];
    const float* gcnb  = (const float*)d_in[7];
    const float* lng   = (const float*)d_in[8];
    const float* lnb   = (const float*)d_in[9];

    float* X = (float*)d_out;                                   // [N,128] fp32
    unsigned short* Xs = (unsigned short*)d_ws;                 // [N,128] bf16
    unsigned short* Gb = Xs + (size_t)N_NODES * HIDDEN;         // [N,128] bf16
    unsigned short* Wt = Gb;                                    // [112,640] bf16 (overlaps Gb: dead before gather)
    unsigned short* Wt2 = Gb + (size_t)N_NODES * HIDDEN;        // [2,128,128] bf16
    float* dis = (float*)(Wt2 + 2 * HIDDEN * HIDDEN);           // [N]
    int* cnt  = (int*)(dis + N_NODES);                          // [N]
    int* pos  = cnt + N_NODES;                                  // [N] (separate: one memset zeroes cnt+pos)
    int* offs = pos + N_NODES;                                  // [N+1]
    int* bsum = offs + N_NODES + 1;                             // [128]
    int* bpre = bsum + 128;                                     // [128]
    int* srcs = bpre + 128;                                     // [E]

    hipMemsetAsync(cnt, 0, 2 * N_NODES * sizeof(int), stream);  // cnt + pos in one shot
    deg_count<<<(E_EDGES + 255) / 256, 256, 0, stream>>>(eidx, cnt);
    make_dis<<<(N_NODES + 255) / 256, 256, 0, stream>>>(cnt, dis);
    scan_blocksum<<<NB_SCAN, 256, 0, stream>>>(cnt, bsum);
    scan_bsum<<<1, 128, 0, stream>>>(bsum, bpre);
    scan_offs<<<NB_SCAN, 256, 0, stream>>>(cnt, bpre, offs);
    fill_srcs<<<(E_EDGES + 255) / 256, 256, 0, stream>>>(eidx, offs, pos, srcs);

    conv_weights<<<(POUT * LLM_DIM + 2 * HIDDEN * HIDDEN + 255) / 256, 256, 0, stream>>>(projW, gcnW, Wt, Wt2);

    proj_mfma<<<(N_NODES + 63) / 64, 256, 0, stream>>>(llm, Wt, projb, emb, sid, dis, X, Xs);

    gather<<<(N_NODES + 3) / 4, 256, 0, stream>>>(Xs, offs, srcs, dis, Gb);
    gemm_fin<0><<<(N_NODES + 63) / 64, 256, 0, stream>>>(Gb, Wt2, gcnb, dis, lng, lnb, X, Xs);
    gather<<<(N_NODES + 3) / 4, 256, 0, stream>>>(Xs, offs, srcs, dis, Gb);
    gemm_fin<1><<<(N_NODES + 63) / 64, 256, 0, stream>>>(Gb, Wt2 + HIDDEN * HIDDEN, gcnb + HIDDEN, dis, lng, lnb, X, Xs);
}